// Round 1
// baseline (180.414 us; speedup 1.0000x reference)
//
#include <hip/hip_runtime.h>

// AdaptedGaussianConditional: v = inputs - means; nearest-codebook symbol via
// lower_bound over sorted 256-entry codebook (tie -> lower index); dequant =
// codebook[sym] + means. Outputs concatenated: [dequant fp32 N | symbols-as-f32 N].

#define LVL 256

__global__ __launch_bounds__(256) void agc_quant_kernel(
    const float* __restrict__ inputs,
    const float* __restrict__ means,
    const float* __restrict__ uv,
    float* __restrict__ out_deq,
    float* __restrict__ out_sym,
    int n4, int n)
{
    __shared__ float s_uv[LVL];
    // 256 threads stage the 256-entry codebook
    s_uv[threadIdx.x] = uv[threadIdx.x];
    __syncthreads();

    int i = blockIdx.x * blockDim.x + threadIdx.x;
    if (i < n4) {
        float4 in = reinterpret_cast<const float4*>(inputs)[i];
        float4 mn = reinterpret_cast<const float4*>(means)[i];

        float vs[4] = {in.x - mn.x, in.y - mn.y, in.z - mn.z, in.w - mn.w};
        float ms[4] = {mn.x, mn.y, mn.z, mn.w};
        float dq[4], sy[4];

        #pragma unroll
        for (int k = 0; k < 4; ++k) {
            float v = vs[k];
            // lower_bound: first idx with s_uv[idx] >= v, result in [0, 256]
            int lo = 0, hi = LVL;
            #pragma unroll
            for (int s = 0; s < 8; ++s) {
                int mid = (lo + hi) >> 1;
                bool go_right = (s_uv[mid] < v);
                lo = go_right ? (mid + 1) : lo;
                hi = go_right ? hi : mid;
            }
            int idx = min(max(lo, 1), LVL - 1);
            float left  = s_uv[idx - 1];
            float right = s_uv[idx];
            bool take_left = (fabsf(v - left) <= fabsf(v - right));
            int   sym = take_left ? (idx - 1) : idx;
            float val = take_left ? left : right;
            dq[k] = val + ms[k];
            sy[k] = (float)sym;
        }

        reinterpret_cast<float4*>(out_deq)[i] = make_float4(dq[0], dq[1], dq[2], dq[3]);
        reinterpret_cast<float4*>(out_sym)[i] = make_float4(sy[0], sy[1], sy[2], sy[3]);
    }

    // tail (n not divisible by 4) — handled by one thread; n here is 12.58M, rem=0
    if (blockIdx.x == 0 && threadIdx.x == 0) {
        for (int j = n4 * 4; j < n; ++j) {
            float m = means[j];
            float v = inputs[j] - m;
            int lo = 0, hi = LVL;
            for (int s = 0; s < 8; ++s) {
                int mid = (lo + hi) >> 1;
                bool go_right = (s_uv[mid] < v);
                lo = go_right ? (mid + 1) : lo;
                hi = go_right ? hi : mid;
            }
            int idx = min(max(lo, 1), LVL - 1);
            float left  = s_uv[idx - 1];
            float right = s_uv[idx];
            bool take_left = (fabsf(v - left) <= fabsf(v - right));
            int   sym = take_left ? (idx - 1) : idx;
            float val = take_left ? left : right;
            out_deq[j] = val + m;
            out_sym[j] = (float)sym;
        }
    }
}

extern "C" void kernel_launch(void* const* d_in, const int* in_sizes, int n_in,
                              void* d_out, int out_size, void* d_ws, size_t ws_size,
                              hipStream_t stream) {
    const float* inputs = (const float*)d_in[0];
    const float* means  = (const float*)d_in[1];
    const float* uv     = (const float*)d_in[2];

    int n  = in_sizes[0];        // 12,582,912
    int n4 = n / 4;

    float* out     = (float*)d_out;
    float* out_deq = out;        // first N: dequant
    float* out_sym = out + n;    // second N: symbols (as exact float values)

    int threads = 256;
    int blocks  = (n4 + threads - 1) / threads;
    agc_quant_kernel<<<blocks, threads, 0, stream>>>(
        inputs, means, uv, out_deq, out_sym, n4, n);
}